// Round 1
// baseline (150.697 us; speedup 1.0000x reference)
//
#include <hip/hip_runtime.h>

typedef short  s16x8  __attribute__((ext_vector_type(8)));
typedef float  f32x16 __attribute__((ext_vector_type(16)));
typedef unsigned short u16;
typedef unsigned int   u32;
typedef unsigned long long u64b;

#define MFMA32(a,b,c) __builtin_amdgcn_mfma_f32_32x32x16_bf16((a),(b),(c),0,0,0)
#define KCLS 100

__device__ __forceinline__ u16 f2bf(float f) {
  return (u16)(__builtin_bit_cast(unsigned, f) >> 16);   // trunc; error budget huge
}

__device__ __forceinline__ u32 pk2bf(float lo, float hi) {   // trunc-pack 2 f32 -> 2 bf16
  return (__builtin_bit_cast(u32, lo) >> 16) | (__builtin_bit_cast(u32, hi) & 0xffff0000u);
}

__device__ __forceinline__ float tanh_fast(float x) {
  float e = __builtin_amdgcn_exp2f(x * 2.8853900817779268f);
  return 1.0f - 2.0f * __builtin_amdgcn_rcpf(e + 1.0f);
}

// ============ prep: emit fragment-ordered bf16 tensors + zero accumulators ============
// Fragment = 1 KB: [lane64][8 bf16]; lane&31 = row/col-in-tile, lane>>5 = k-half.
// xF  [b][frag = gks*2+ph]   p = ph*32+(lane&31), c = gks*16+(lane>>5)*8+j
// W1F [k][frag = gks*2+mt]   m = mt*32+(lane&31), c as above
// W2F [k][frag = kb*4+m4]    m = m4*32+(lane&31), c = kb*16+(lane>>5)*8+j
// W3F [k][frag = kb]         m = lane&31,         c = kb*16+(lane>>5)*8+j
__global__ void prep(const float* __restrict__ x, const float* __restrict__ w1,
                     const float* __restrict__ w2, const float* __restrict__ w3,
                     u16* __restrict__ xF, u16* __restrict__ W1F,
                     u16* __restrict__ W2F, u16* __restrict__ W3F,
                     float* __restrict__ fz, float* __restrict__ out2) {
  __shared__ float tile[64][65];
  const int bid = blockIdx.x, t = threadIdx.x;
  if (bid == 0 && t < 2) out2[t] = 0.f;
  if (bid < 512) {                                // ---- x: block = (b, ck) ----
    const int b = bid >> 3, ck = bid & 7;
    #pragma unroll
    for (int j = 0; j < 4; j++) {                 // coalesced fp32 tile (64c x 64p)
      int e4 = j * 1024 + t * 4;
      int c = e4 >> 6, p0 = e4 & 63;
      float4 v = *(const float4*)(x + ((size_t)b * 512 + ck * 64 + c) * 64 + p0);
      tile[c][p0] = v.x; tile[c][p0 + 1] = v.y; tile[c][p0 + 2] = v.z; tile[c][p0 + 3] = v.w;
    }
    __syncthreads();
    #pragma unroll
    for (int i = 0; i < 2; i++) {                 // 512 16B-slots
      int s = i * 256 + t;
      int ksl = s >> 7, ph = (s >> 6) & 1, lane = s & 63;
      int cb = ksl * 16 + (lane >> 5) * 8, pp = ph * 32 + (lane & 31);
      u16 o[8];
      #pragma unroll
      for (int jj = 0; jj < 8; jj++) o[jj] = f2bf(tile[cb + jj][pp]);
      *(uint4*)(xF + (((size_t)b * 64 + (ck * 4 + ksl) * 2 + ph) * 512) + lane * 8) = *(uint4*)o;
    }
  } else if (bid < 1312) {                        // ---- W1: 6400 frags ----
    int base = (bid - 512) * 512;
    #pragma unroll
    for (int i = 0; i < 2; i++) {
      int s = base + i * 256 + t;
      int frag = s >> 6, lane = s & 63;
      int k = frag >> 6, fr = frag & 63;
      int m = (fr & 1) * 32 + (lane & 31);
      int c0 = (fr >> 1) * 16 + (lane >> 5) * 8;
      const float* src = w1 + ((size_t)k * 64 + m) * 512 + c0;
      float4 a = *(const float4*)src, b4 = *(const float4*)(src + 4);
      u16 o[8] = { f2bf(a.x), f2bf(a.y), f2bf(a.z), f2bf(a.w),
                   f2bf(b4.x), f2bf(b4.y), f2bf(b4.z), f2bf(b4.w) };
      *(uint4*)(W1F + ((size_t)frag * 512) + lane * 8) = *(uint4*)o;
    }
  } else if (bid < 1512) {                        // ---- W2: 1600 frags ----
    int base = (bid - 1312) * 512;
    #pragma unroll
    for (int i = 0; i < 2; i++) {
      int s = base + i * 256 + t;
      int frag = s >> 6, lane = s & 63;
      int k = frag >> 4, fr = frag & 15;
      int m = (fr & 3) * 32 + (lane & 31);
      int c0 = (fr >> 2) * 16 + (lane >> 5) * 8;
      const float* src = w2 + ((size_t)k * 128 + m) * 64 + c0;
      float4 a = *(const float4*)src, b4 = *(const float4*)(src + 4);
      u16 o[8] = { f2bf(a.x), f2bf(a.y), f2bf(a.z), f2bf(a.w),
                   f2bf(b4.x), f2bf(b4.y), f2bf(b4.z), f2bf(b4.w) };
      *(uint4*)(W2F + ((size_t)frag * 512) + lane * 8) = *(uint4*)o;
    }
  } else if (bid < 1612) {                        // ---- W3: 800 frags ----
    int base = (bid - 1512) * 512;
    #pragma unroll
    for (int i = 0; i < 2; i++) {
      int s = base + i * 256 + t;
      int frag = s >> 6, lane = s & 63;
      int k = frag >> 3, kb = frag & 7;
      int m = lane & 31;
      int c0 = kb * 16 + (lane >> 5) * 8;
      const float* src = w3 + ((size_t)k * 32 + m) * 128 + c0;
      float4 a = *(const float4*)src, b4 = *(const float4*)(src + 4);
      u16 o[8] = { f2bf(a.x), f2bf(a.y), f2bf(a.z), f2bf(a.w),
                   f2bf(b4.x), f2bf(b4.y), f2bf(b4.z), f2bf(b4.w) };
      *(uint4*)(W3F + ((size_t)frag * 512) + lane * 8) = *(uint4*)o;
    }
  } else {                                        // ---- zero fw/f1w (12800 floats) ----
    int i4 = (bid - 1612) * 256 + t;
    if (i4 < 3200) {
      float4 z = {0.f, 0.f, 0.f, 0.f};
      *(float4*)(fz + (size_t)i4 * 4) = z;
    }
  }
}

// ============ in-register C/D -> B-fragment handoff (T12-style) ============
// Input: acc of ONE 32-row C/D tile: reg g*4+q holds act-row r = q+8g+4h (h=lane>>5),
// col = lane&31. Output: B-frag covering k-rows [GG*16, GG*16+16):
//   element (lane h,nn)[j] = bf16(tanh(act[GG*16 + h*8 + j][nn])).
// Derivation: row GG*16 + h_dest*8 + jh*4 + q  ==  q + 8*(2GG+h_dest) + 4*jh
//   -> source lane-half = jh, source reg-g = 2GG + h_dest.
// So P* (g=2GG) / Q* (g=2GG+1) packed pairs + one permlane32_swap per pair:
//   after swap(P,Q): P' = {P_lo, Q_lo} -> j-low half, Q' = {P_hi, Q_hi} -> j-high half.
template<int GG>
__device__ __forceinline__ s16x8 mk_bfrag(const f32x16 a) {
  u32 P0 = pk2bf(tanh_fast(a[8 * GG + 0]), tanh_fast(a[8 * GG + 1]));
  u32 P1 = pk2bf(tanh_fast(a[8 * GG + 2]), tanh_fast(a[8 * GG + 3]));
  u32 Q0 = pk2bf(tanh_fast(a[8 * GG + 4]), tanh_fast(a[8 * GG + 5]));
  u32 Q1 = pk2bf(tanh_fast(a[8 * GG + 6]), tanh_fast(a[8 * GG + 7]));
  asm("v_permlane32_swap_b32 %0, %1" : "+v"(P0), "+v"(Q0));
  asm("v_permlane32_swap_b32 %0, %1" : "+v"(P1), "+v"(Q1));
  int4 wv = { (int)P0, (int)P1, (int)Q0, (int)Q1 };   // (j0,j1)(j2,j3)(j4,j5)(j6,j7)
  return __builtin_bit_cast(s16x8, wv);
}

// ============ main: block = (k, b-pair); waves = (bq, ph); NO LDS, NO barriers ====
// Each wave owns a p-half (N=32) and carries the full chain h1->h2->lt in registers:
// stage-s B-operands come from the same wave's stage-(s-1) accumulators via
// permlane32_swap, so the LDS round-trips + all 8 barriers of the previous
// structure are gone. Waves free-run -> MFMA/VALU phases of different waves
// overlap without any pipelining machinery. All 4 waves stream the same
// W-fragments (L1 temporal locality); VGPR cap 128 (acc2 = 64) -> 4 blocks/CU.
__global__ __launch_bounds__(256, 4) void cssr_main(
    const u16* __restrict__ W1F, const u16* __restrict__ W2F, const u16* __restrict__ W3F,
    const u16* __restrict__ xF, const float* __restrict__ protos,
    const float* __restrict__ protos1, float* __restrict__ out,
    float* __restrict__ fw, float* __restrict__ f1w)
{
  const int bid = blockIdx.x;
  const int k = bid >> 5, bp = bid & 31;
  const int tid = threadIdx.x, w = tid >> 6, lane = tid & 63;
  const int bq = w >> 1, ph = w & 1;
  const int b = bp * 2 + bq;
  const int h = lane >> 5, nn = lane & 31;

  const u16* xb  = xF  + ((size_t)b * 64) * 512 + lane * 8;
  const u16* Wk1 = W1F + ((size_t)k * 64) * 512 + lane * 8;

  // ---------------- stage 1: h1 = tanh(W1[k] @ x[b])  per-wave M=64 N=32 K=512 ----
  f32x16 acc1[2] = {};
  #pragma unroll
  for (int ksl = 0; ksl < 32; ksl++) {
    s16x8 B  = *(const s16x8*)(xb  + (ksl * 2 + ph) * 512);
    s16x8 A0 = *(const s16x8*)(Wk1 + (ksl * 2 + 0) * 512);
    s16x8 A1 = *(const s16x8*)(Wk1 + (ksl * 2 + 1) * 512);
    acc1[0] = MFMA32(A0, B, acc1[0]);
    acc1[1] = MFMA32(A1, B, acc1[1]);
  }

  // handoff 1 (in-register): b1[kb] covers h1-channels [kb*16, kb*16+16)
  s16x8 b1[4];
  b1[0] = mk_bfrag<0>(acc1[0]); b1[1] = mk_bfrag<1>(acc1[0]);
  b1[2] = mk_bfrag<0>(acc1[1]); b1[3] = mk_bfrag<1>(acc1[1]);

  // ---------------- stage 2: h2 = tanh(W2[k] @ h1)  per-wave M=128 N=32 K=64 ----
  const u16* Wk2 = W2F + ((size_t)k * 16) * 512 + lane * 8;
  f32x16 acc2[4] = {};
  #pragma unroll
  for (int kb = 0; kb < 4; kb++) {
    #pragma unroll
    for (int m4 = 0; m4 < 4; m4++) {
      s16x8 A = *(const s16x8*)(Wk2 + (kb * 4 + m4) * 512);
      acc2[m4] = MFMA32(A, b1[kb], acc2[m4]);
    }
  }

  // handoff 2 (in-register): b2[mt2*2+gg] covers h2-channels mt2*32 + gg*16 + ...
  s16x8 b2[8];
  b2[0] = mk_bfrag<0>(acc2[0]); b2[1] = mk_bfrag<1>(acc2[0]);
  b2[2] = mk_bfrag<0>(acc2[1]); b2[3] = mk_bfrag<1>(acc2[1]);
  b2[4] = mk_bfrag<0>(acc2[2]); b2[5] = mk_bfrag<1>(acc2[2]);
  b2[6] = mk_bfrag<0>(acc2[3]); b2[7] = mk_bfrag<1>(acc2[3]);

  // ---------------- stage 3: lt = tanh(W3[k] @ h2)  per-wave M=32 N=32 K=128 ----
  const u16* Wk3 = W3F + ((size_t)k * 8) * 512 + lane * 8;
  f32x16 acc3 = {};
  #pragma unroll
  for (int kb = 0; kb < 8; kb++) {
    s16x8 A = *(const s16x8*)(Wk3 + kb * 512);
    acc3 = MFMA32(A, b2[kb], acc3);
  }

  // ---------------- distances, clip, logits, f / f1 ----------------
  const int p = ph * 32 + nn;
  const float* pr  = protos  + (size_t)k * 2048 + p;
  const float* pr1 = protos1 + (size_t)k * 2048 + p;
  float d2 = 0.f, d21 = 0.f;
  #pragma unroll
  for (int g = 0; g < 4; g++) {
    #pragma unroll
    for (int q = 0; q < 4; q++) {
      int m = q + 8 * g + 4 * h;
      float lt = tanh_fast(acc3[g * 4 + q]);
      float d = lt - pr [m * 64];  d2  += d * d;
      float e = lt - pr1[m * 64];  d21 += e * e;
    }
  }
  d2 += __shfl_xor(d2, 32); d21 += __shfl_xor(d21, 32);
  float er  = fminf(fmaxf(d2  * -0.1f, -100.f), 100.f);
  float er1 = fminf(fmaxf(d21 * -0.1f, -100.f), 100.f);
  if (h == 0) {
    out[(size_t)b * 6400 + k * 64 + p]          = er;
    out[409600 + (size_t)b * 6400 + k * 64 + p] = er1;
  }
  float s = er, s1 = er1;
  s += __shfl_xor(s, 1);  s1 += __shfl_xor(s1, 1);
  s += __shfl_xor(s, 2);  s1 += __shfl_xor(s1, 2);
  s += __shfl_xor(s, 4);  s1 += __shfl_xor(s1, 4);
  s += __shfl_xor(s, 8);  s1 += __shfl_xor(s1, 8);
  s += __shfl_xor(s, 16); s1 += __shfl_xor(s1, 16);
  if (lane == 0) {
    atomicAdd(&fw [k * 64 + b], s);    // two waves (ph=0,1) contribute per (k,b)
    atomicAdd(&f1w[k * 64 + b], s1);
  }
}

// ============ finalize: per-k block, atomicAdd into out2 (zeroed in prep) ============
__global__ void finalize(const float* __restrict__ f, const float* __restrict__ f1,
                         const int* __restrict__ ycls, float* __restrict__ out2) {
  const int k = blockIdx.x, b = threadIdx.x;
  float fv = f[k * 64 + b], f1v = f1[k * 64 + b];
  bool eq = (ycls[b] == k);
  bool cb = (!eq) && (fv < 10000.f);
  float s1 = eq ? f1v : 0.f, ne = eq ? 1.f : 0.f;
  float s  = cb ? fv  : 0.f, nc = cb ? 1.f : 0.f;
  #pragma unroll
  for (int o = 1; o < 64; o <<= 1) {
    s1 += __shfl_xor(s1, o); ne += __shfl_xor(ne, o);
    s  += __shfl_xor(s,  o); nc += __shfl_xor(nc, o);
  }
  if (b == 0) {
    if (ne > 0.f) atomicAdd(&out2[0], s1 / ne);
    if (nc > 0.f) atomicAdd(&out2[1], s / nc);
  }
}

extern "C" void kernel_launch(void* const* d_in, const int* in_sizes, int n_in,
                              void* d_out, int out_size, void* d_ws, size_t ws_size,
                              hipStream_t stream) {
  const float* x     = (const float*)d_in[0];
  const int*   ycls  = (const int*)d_in[1];
  const float* W1    = (const float*)d_in[4];
  const float* W2    = (const float*)d_in[5];
  const float* W3    = (const float*)d_in[6];
  const float* prot  = (const float*)d_in[7];
  const float* prot1 = (const float*)d_in[8];
  float* out = (float*)d_out;

  char* ws = (char*)d_ws;
  u16*  xFb = (u16*)(ws);                        // 4,194,304 B
  u16*  W1F = (u16*)(ws + 4194304);              // 6,553,600 B
  u16*  W2F = (u16*)(ws + 10747904);             // 1,638,400 B
  u16*  W3F = (u16*)(ws + 12386304);             //   819,200 B
  float* fw  = (float*)(ws + 13205504);          // 25,600 B
  float* f1w = (float*)(ws + 13231104);          // 25,600 B (contiguous with fw)

  prep<<<1625, 256, 0, stream>>>(x, W1, W2, W3, xFb, W1F, W2F, W3F,
                                 fw, out + 819200);
  cssr_main<<<KCLS * 32, 256, 0, stream>>>(W1F, W2F, W3F, xFb, prot, prot1,
                                           out, fw, f1w);
  finalize<<<KCLS, 64, 0, stream>>>(fw, f1w, ycls, out + 819200);
}

// Round 2
// 144.928 us; speedup vs baseline: 1.0398x; 1.0398x over previous
//
#include <hip/hip_runtime.h>

typedef short  s16x8  __attribute__((ext_vector_type(8)));
typedef float  f32x16 __attribute__((ext_vector_type(16)));
typedef unsigned short u16;
typedef unsigned int   u32;
typedef unsigned long long u64b;

#define MFMA32(a,b,c) __builtin_amdgcn_mfma_f32_32x32x16_bf16((a),(b),(c),0,0,0)
#define KCLS 100
#define VMCNT(n) asm volatile("s_waitcnt vmcnt(" #n ")" ::: "memory")
#define BAR()    __builtin_amdgcn_s_barrier()
#define SCHEDB() __builtin_amdgcn_sched_barrier(0)

__device__ __forceinline__ u16 f2bf(float f) {
  return (u16)(__builtin_bit_cast(unsigned, f) >> 16);   // trunc; error budget huge
}

__device__ __forceinline__ u32 pk2bf(float lo, float hi) {   // trunc-pack 2 f32 -> 2 bf16
  return (__builtin_bit_cast(u32, lo) >> 16) | (__builtin_bit_cast(u32, hi) & 0xffff0000u);
}

__device__ __forceinline__ float tanh_fast(float x) {
  float e = __builtin_amdgcn_exp2f(x * 2.8853900817779268f);
  return 1.0f - 2.0f * __builtin_amdgcn_rcpf(e + 1.0f);
}

__device__ __forceinline__ void ld_lds16(const void* g, void* l) {
  __builtin_amdgcn_global_load_lds(
      (const __attribute__((address_space(1))) unsigned char*)g,
      (__attribute__((address_space(3))) unsigned char*)l, 16, 0, 0);
}

// ============ prep: emit fragment-ordered bf16 tensors + zero accumulators ============
// Fragment = 1 KB: [lane64][8 bf16]; lane&31 = row/col-in-tile, lane>>5 = k-half.
// xF  [b][frag = gks*2+ph]   p = ph*32+(lane&31), c = gks*16+(lane>>5)*8+j
// W1F [k][frag = gks*2+mt]   m = mt*32+(lane&31), c as above
// W2F [k][frag = kb*4+m4]    m = m4*32+(lane&31), c = kb*16+(lane>>5)*8+j
// W3F [k][frag = kb]         m = lane&31,         c = kb*16+(lane>>5)*8+j
__global__ void prep(const float* __restrict__ x, const float* __restrict__ w1,
                     const float* __restrict__ w2, const float* __restrict__ w3,
                     u16* __restrict__ xF, u16* __restrict__ W1F,
                     u16* __restrict__ W2F, u16* __restrict__ W3F,
                     float* __restrict__ fz, float* __restrict__ out2) {
  __shared__ float tile[64][65];
  const int bid = blockIdx.x, t = threadIdx.x;
  if (bid == 0 && t < 2) out2[t] = 0.f;
  if (bid < 512) {                                // ---- x: block = (b, ck) ----
    const int b = bid >> 3, ck = bid & 7;
    #pragma unroll
    for (int j = 0; j < 4; j++) {                 // coalesced fp32 tile (64c x 64p)
      int e4 = j * 1024 + t * 4;
      int c = e4 >> 6, p0 = e4 & 63;
      float4 v = *(const float4*)(x + ((size_t)b * 512 + ck * 64 + c) * 64 + p0);
      tile[c][p0] = v.x; tile[c][p0 + 1] = v.y; tile[c][p0 + 2] = v.z; tile[c][p0 + 3] = v.w;
    }
    __syncthreads();
    #pragma unroll
    for (int i = 0; i < 2; i++) {                 // 512 16B-slots
      int s = i * 256 + t;
      int ksl = s >> 7, ph = (s >> 6) & 1, lane = s & 63;
      int cb = ksl * 16 + (lane >> 5) * 8, pp = ph * 32 + (lane & 31);
      u16 o[8];
      #pragma unroll
      for (int jj = 0; jj < 8; jj++) o[jj] = f2bf(tile[cb + jj][pp]);
      *(uint4*)(xF + (((size_t)b * 64 + (ck * 4 + ksl) * 2 + ph) * 512) + lane * 8) = *(uint4*)o;
    }
  } else if (bid < 1312) {                        // ---- W1: 6400 frags ----
    int base = (bid - 512) * 512;
    #pragma unroll
    for (int i = 0; i < 2; i++) {
      int s = base + i * 256 + t;
      int frag = s >> 6, lane = s & 63;
      int k = frag >> 6, fr = frag & 63;
      int m = (fr & 1) * 32 + (lane & 31);
      int c0 = (fr >> 1) * 16 + (lane >> 5) * 8;
      const float* src = w1 + ((size_t)k * 64 + m) * 512 + c0;
      float4 a = *(const float4*)src, b4 = *(const float4*)(src + 4);
      u16 o[8] = { f2bf(a.x), f2bf(a.y), f2bf(a.z), f2bf(a.w),
                   f2bf(b4.x), f2bf(b4.y), f2bf(b4.z), f2bf(b4.w) };
      *(uint4*)(W1F + ((size_t)frag * 512) + lane * 8) = *(uint4*)o;
    }
  } else if (bid < 1512) {                        // ---- W2: 1600 frags ----
    int base = (bid - 1312) * 512;
    #pragma unroll
    for (int i = 0; i < 2; i++) {
      int s = base + i * 256 + t;
      int frag = s >> 6, lane = s & 63;
      int k = frag >> 4, fr = frag & 15;
      int m = (fr & 3) * 32 + (lane & 31);
      int c0 = (fr >> 2) * 16 + (lane >> 5) * 8;
      const float* src = w2 + ((size_t)k * 128 + m) * 64 + c0;
      float4 a = *(const float4*)src, b4 = *(const float4*)(src + 4);
      u16 o[8] = { f2bf(a.x), f2bf(a.y), f2bf(a.z), f2bf(a.w),
                   f2bf(b4.x), f2bf(b4.y), f2bf(b4.z), f2bf(b4.w) };
      *(uint4*)(W2F + ((size_t)frag * 512) + lane * 8) = *(uint4*)o;
    }
  } else if (bid < 1612) {                        // ---- W3: 800 frags ----
    int base = (bid - 1512) * 512;
    #pragma unroll
    for (int i = 0; i < 2; i++) {
      int s = base + i * 256 + t;
      int frag = s >> 6, lane = s & 63;
      int k = frag >> 3, kb = frag & 7;
      int m = lane & 31;
      int c0 = kb * 16 + (lane >> 5) * 8;
      const float* src = w3 + ((size_t)k * 32 + m) * 128 + c0;
      float4 a = *(const float4*)src, b4 = *(const float4*)(src + 4);
      u16 o[8] = { f2bf(a.x), f2bf(a.y), f2bf(a.z), f2bf(a.w),
                   f2bf(b4.x), f2bf(b4.y), f2bf(b4.z), f2bf(b4.w) };
      *(uint4*)(W3F + ((size_t)frag * 512) + lane * 8) = *(uint4*)o;
    }
  } else {                                        // ---- zero fw/f1w (12800 floats) ----
    int i4 = (bid - 1612) * 256 + t;
    if (i4 < 3200) {
      float4 z = {0.f, 0.f, 0.f, 0.f};
      *(float4*)(fz + (size_t)i4 * 4) = z;
    }
  }
}

// ============ in-register C/D -> B-fragment handoff (T12-style) ============
// acc reg g*4+q holds act-row r = q+8g+4h (h=lane>>5), col = lane&31.
// Output B-frag covers act-rows [GG*16, GG*16+16): elem (half h, col nn)[j] =
// bf16(tanh(act[GG*16 + h*8 + j][nn])). One permlane32_swap per packed pair.
template<int GG>
__device__ __forceinline__ s16x8 mk_bfrag(const f32x16 a) {
  u32 P0 = pk2bf(tanh_fast(a[8 * GG + 0]), tanh_fast(a[8 * GG + 1]));
  u32 P1 = pk2bf(tanh_fast(a[8 * GG + 2]), tanh_fast(a[8 * GG + 3]));
  u32 Q0 = pk2bf(tanh_fast(a[8 * GG + 4]), tanh_fast(a[8 * GG + 5]));
  u32 Q1 = pk2bf(tanh_fast(a[8 * GG + 6]), tanh_fast(a[8 * GG + 7]));
  asm("v_permlane32_swap_b32 %0, %1" : "+v"(P0), "+v"(Q0));
  asm("v_permlane32_swap_b32 %0, %1" : "+v"(P1), "+v"(Q1));
  int4 wv = { (int)P0, (int)P1, (int)Q0, (int)Q1 };   // (j0,j1)(j2,j3)(j4,j5)(j6,j7)
  return __builtin_bit_cast(s16x8, wv);
}

// ============ main: block = (k, b-pair); waves = (bq, ph) ============
// In-register T12 handoffs between stages (no handoff LDS, no bank conflicts) +
// counted-vmcnt DMA pipeline for operand delivery (T3+T4): all W/x fragments
// arrive via global_load_lds in 4-ksl chunks, double-buffered; vmcnt is never
// drained to 0 inside the main loop, so loads stay in flight across barriers.
// LDS = 48 KB -> 3 blocks/CU; W fragments hit L2 once per block (4x cut vs r1).
__global__ __launch_bounds__(256, 3) void cssr_main(
    const u16* __restrict__ W1F, const u16* __restrict__ W2F, const u16* __restrict__ W3F,
    const u16* __restrict__ xF, const float* __restrict__ protos,
    const float* __restrict__ protos1, float* __restrict__ out,
    float* __restrict__ fw, float* __restrict__ f1w)
{
  __shared__ u16 pool[2][12288];     // 2 x 24 KB chunk buffers
  const int bid = blockIdx.x;
  const int k = bid >> 5, bpair = bid & 31;
  const int tid = threadIdx.x, w = tid >> 6, lane = tid & 63;
  const int bq = w >> 1, ph = w & 1;
  const int b = bpair * 2 + bq;
  const int h = lane >> 5, nn = lane & 31;

  // chunk frag map: f 0..7 = W1 (ksl*2+mt); f 8..23 = x, f = 8 + wave*4 + ksl
  // (so wave w's B-frags sit at 8+w*4+ksl). Wave w stages f = w*6 .. w*6+5.
  const u16* sp[6];
  int dfo[6];
  #pragma unroll
  for (int i = 0; i < 6; i++) {
    int f = w * 6 + i;
    dfo[i] = f * 512;
    if (f < 8) {
      int ksl = f >> 1, mt = f & 1;
      sp[i] = W1F + ((size_t)k * 64 + ksl * 2 + mt) * 512 + lane * 8;
    } else {
      int g = f - 8, wv = g >> 2, ksl = g & 3;
      int bs = bpair * 2 + (wv >> 1), ps = wv & 1;
      sp[i] = xF + ((size_t)bs * 64 + ksl * 2 + ps) * 512 + lane * 8;
    }
  }

  // prologue: stage chunk 0
  #pragma unroll
  for (int i = 0; i < 6; i++) { ld_lds16(sp[i], &pool[0][dfo[i]]); sp[i] += 4096; }
  VMCNT(0); BAR();

  // ---------------- stage 1: h1 = tanh(W1[k] @ x[b])  per-wave M=64 N=32 K=512 ----
  f32x16 acc1[2] = {};
  #pragma unroll
  for (int ci = 0; ci < 8; ci++) {
    const int cb = ci & 1;
    if (ci < 7) {                    // prefetch chunk ci+1 (6 loads, counted wait)
      #pragma unroll
      for (int i = 0; i < 6; i++) { ld_lds16(sp[i], &pool[cb ^ 1][dfo[i]]); sp[i] += 4096; }
      VMCNT(6);
    } else {                         // last chunk: stage W2 (16 frags) into pool[0]
      #pragma unroll
      for (int j = 0; j < 4; j++) {
        int f = w * 4 + j;
        ld_lds16(W2F + ((size_t)k * 16 + f) * 512 + lane * 8, &pool[0][f * 512]);
      }
      VMCNT(4);
    }
    BAR(); SCHEDB();                 // chunk ci fully resident
    const u16* bu = pool[cb];
    #pragma unroll
    for (int ksl = 0; ksl < 4; ksl++) {
      s16x8 A0 = *(const s16x8*)(bu + (ksl * 2 + 0) * 512 + lane * 8);
      s16x8 A1 = *(const s16x8*)(bu + (ksl * 2 + 1) * 512 + lane * 8);
      s16x8 B  = *(const s16x8*)(bu + (8 + w * 4 + ksl) * 512 + lane * 8);
      acc1[0] = MFMA32(A0, B, acc1[0]);
      acc1[1] = MFMA32(A1, B, acc1[1]);
    }
    BAR();                           // all reads of buf cb done -> reusable for DMA
  }

  // stage W3 (8 frags) into pool[1] (chunk-7 reads fenced by the loop's last BAR)
  #pragma unroll
  for (int j = 0; j < 2; j++) {
    int f = w * 2 + j;
    ld_lds16(W3F + ((size_t)k * 8 + f) * 512 + lane * 8, &pool[1][f * 512]);
  }

  // handoff 1 (in-register, VALU overlaps W2/W3 DMA): b1[kb] = h1 ch [kb*16,kb*16+16)
  s16x8 b1[4];
  b1[0] = mk_bfrag<0>(acc1[0]); b1[1] = mk_bfrag<1>(acc1[0]);
  b1[2] = mk_bfrag<0>(acc1[1]); b1[3] = mk_bfrag<1>(acc1[1]);

  VMCNT(2); BAR(); SCHEDB();         // W2 resident (W3 still in flight)

  // ---------------- stage 2: h2 = tanh(W2[k] @ h1)  per-wave M=128 N=32 K=64 ----
  f32x16 acc2[4] = {};
  #pragma unroll
  for (int kb = 0; kb < 4; kb++) {
    #pragma unroll
    for (int m4 = 0; m4 < 4; m4++) {
      s16x8 A = *(const s16x8*)(&pool[0][(kb * 4 + m4) * 512] + lane * 8);
      acc2[m4] = MFMA32(A, b1[kb], acc2[m4]);
    }
  }

  // handoff 2
  s16x8 b2[8];
  b2[0] = mk_bfrag<0>(acc2[0]); b2[1] = mk_bfrag<1>(acc2[0]);
  b2[2] = mk_bfrag<0>(acc2[1]); b2[3] = mk_bfrag<1>(acc2[1]);
  b2[4] = mk_bfrag<0>(acc2[2]); b2[5] = mk_bfrag<1>(acc2[2]);
  b2[6] = mk_bfrag<0>(acc2[3]); b2[7] = mk_bfrag<1>(acc2[3]);

  VMCNT(0); BAR(); SCHEDB();         // W3 resident

  // prefetch protos into regs (latency hides under stage-3 MFMAs)
  const int p = ph * 32 + nn;
  const float* pr  = protos  + (size_t)k * 2048 + p;
  const float* pr1 = protos1 + (size_t)k * 2048 + p;
  float prv[16], pr1v[16];
  #pragma unroll
  for (int g = 0; g < 4; g++) {
    #pragma unroll
    for (int q = 0; q < 4; q++) {
      int m = q + 8 * g + 4 * h;
      prv [g * 4 + q] = pr [m * 64];
      pr1v[g * 4 + q] = pr1[m * 64];
    }
  }

  // ---------------- stage 3: lt = tanh(W3[k] @ h2)  per-wave M=32 N=32 K=128 ----
  f32x16 acc3 = {};
  #pragma unroll
  for (int kb = 0; kb < 8; kb++) {
    s16x8 A = *(const s16x8*)(&pool[1][kb * 512] + lane * 8);
    acc3 = MFMA32(A, b2[kb], acc3);
  }

  // ---------------- distances, clip, logits, f / f1 ----------------
  float d2 = 0.f, d21 = 0.f;
  #pragma unroll
  for (int g = 0; g < 4; g++) {
    #pragma unroll
    for (int q = 0; q < 4; q++) {
      float lt = tanh_fast(acc3[g * 4 + q]);
      float d = lt - prv [g * 4 + q];  d2  += d * d;
      float e = lt - pr1v[g * 4 + q];  d21 += e * e;
    }
  }
  d2 += __shfl_xor(d2, 32); d21 += __shfl_xor(d21, 32);
  float er  = fminf(fmaxf(d2  * -0.1f, -100.f), 100.f);
  float er1 = fminf(fmaxf(d21 * -0.1f, -100.f), 100.f);
  if (h == 0) {
    out[(size_t)b * 6400 + k * 64 + p]          = er;
    out[409600 + (size_t)b * 6400 + k * 64 + p] = er1;
  }
  float s = er, s1 = er1;
  s += __shfl_xor(s, 1);  s1 += __shfl_xor(s1, 1);
  s += __shfl_xor(s, 2);  s1 += __shfl_xor(s1, 2);
  s += __shfl_xor(s, 4);  s1 += __shfl_xor(s1, 4);
  s += __shfl_xor(s, 8);  s1 += __shfl_xor(s1, 8);
  s += __shfl_xor(s, 16); s1 += __shfl_xor(s1, 16);
  if (lane == 0) {
    atomicAdd(&fw [k * 64 + b], s);    // two waves (ph=0,1) contribute per (k,b)
    atomicAdd(&f1w[k * 64 + b], s1);
  }
}

// ============ finalize: per-k block, atomicAdd into out2 (zeroed in prep) ============
__global__ void finalize(const float* __restrict__ f, const float* __restrict__ f1,
                         const int* __restrict__ ycls, float* __restrict__ out2) {
  const int k = blockIdx.x, b = threadIdx.x;
  float fv = f[k * 64 + b], f1v = f1[k * 64 + b];
  bool eq = (ycls[b] == k);
  bool cb = (!eq) && (fv < 10000.f);
  float s1 = eq ? f1v : 0.f, ne = eq ? 1.f : 0.f;
  float s  = cb ? fv  : 0.f, nc = cb ? 1.f : 0.f;
  #pragma unroll
  for (int o = 1; o < 64; o <<= 1) {
    s1 += __shfl_xor(s1, o); ne += __shfl_xor(ne, o);
    s  += __shfl_xor(s,  o); nc += __shfl_xor(nc, o);
  }
  if (b == 0) {
    if (ne > 0.f) atomicAdd(&out2[0], s1 / ne);
    if (nc > 0.f) atomicAdd(&out2[1], s / nc);
  }
}

extern "C" void kernel_launch(void* const* d_in, const int* in_sizes, int n_in,
                              void* d_out, int out_size, void* d_ws, size_t ws_size,
                              hipStream_t stream) {
  const float* x     = (const float*)d_in[0];
  const int*   ycls  = (const int*)d_in[1];
  const float* W1    = (const float*)d_in[4];
  const float* W2    = (const float*)d_in[5];
  const float* W3    = (const float*)d_in[6];
  const float* prot  = (const float*)d_in[7];
  const float* prot1 = (const float*)d_in[8];
  float* out = (float*)d_out;

  char* ws = (char*)d_ws;
  u16*  xFb = (u16*)(ws);                        // 4,194,304 B
  u16*  W1F = (u16*)(ws + 4194304);              // 6,553,600 B
  u16*  W2F = (u16*)(ws + 10747904);             // 1,638,400 B
  u16*  W3F = (u16*)(ws + 12386304);             //   819,200 B
  float* fw  = (float*)(ws + 13205504);          // 25,600 B
  float* f1w = (float*)(ws + 13231104);          // 25,600 B (contiguous with fw)

  prep<<<1625, 256, 0, stream>>>(x, W1, W2, W3, xFb, W1F, W2F, W3F,
                                 fw, out + 819200);
  cssr_main<<<KCLS * 32, 256, 0, stream>>>(W1F, W2F, W3F, xFb, prot, prot1,
                                           out, fw, f1w);
  finalize<<<KCLS, 64, 0, stream>>>(fw, f1w, ycls, out + 819200);
}

// Round 3
// 141.957 us; speedup vs baseline: 1.0616x; 1.0209x over previous
//
#include <hip/hip_runtime.h>

typedef short  s16x8  __attribute__((ext_vector_type(8)));
typedef float  f32x16 __attribute__((ext_vector_type(16)));
typedef unsigned short u16;
typedef unsigned int   u32;
typedef unsigned long long u64b;

#define MFMA32(a,b,c) __builtin_amdgcn_mfma_f32_32x32x16_bf16((a),(b),(c),0,0,0)
#define KCLS 100
#define VMCNT(n) asm volatile("s_waitcnt vmcnt(" #n ")" ::: "memory")
#define BAR()    __builtin_amdgcn_s_barrier()

__device__ __forceinline__ u16 f2bf(float f) {
  return (u16)(__builtin_bit_cast(unsigned, f) >> 16);   // trunc; error budget huge
}

__device__ __forceinline__ u32 pk2bf(float lo, float hi) {   // trunc-pack 2 f32 -> 2 bf16
#if __has_builtin(__builtin_amdgcn_perm)
  // v_perm_b32: dst = {hi.b3, hi.b2, lo.b3, lo.b2}  (1 instr vs shr+and+or)
  return __builtin_amdgcn_perm(__builtin_bit_cast(u32, hi),
                               __builtin_bit_cast(u32, lo), 0x07060302u);
#else
  return (__builtin_bit_cast(u32, lo) >> 16) | (__builtin_bit_cast(u32, hi) & 0xffff0000u);
#endif
}

__device__ __forceinline__ float tanh_fast(float x) {
  float e = __builtin_amdgcn_exp2f(x * 2.8853900817779268f);
  return 1.0f - 2.0f * __builtin_amdgcn_rcpf(e + 1.0f);
}

__device__ __forceinline__ void ld_lds16(const void* g, void* l) {
  __builtin_amdgcn_global_load_lds(
      (const __attribute__((address_space(1))) unsigned char*)g,
      (__attribute__((address_space(3))) unsigned char*)l, 16, 0, 0);
}

// ============ prep: emit fragment-ordered bf16 tensors + zero accumulators ============
// Fragment = 1 KB: [lane64][8 bf16]; lane&31 = row/col-in-tile, lane>>5 = k-half.
// xF  [b][frag = gks*2+ph]   p = ph*32+(lane&31), c = gks*16+(lane>>5)*8+j
// W1F [k][frag = gks*2+mt]   m = mt*32+(lane&31), c as above
// W2F [k][frag = kb*4+m4]    m = m4*32+(lane&31), c = kb*16+(lane>>5)*8+j
// W3F [k][frag = kb]         m = lane&31,         c = kb*16+(lane>>5)*8+j
__global__ void prep(const float* __restrict__ x, const float* __restrict__ w1,
                     const float* __restrict__ w2, const float* __restrict__ w3,
                     u16* __restrict__ xF, u16* __restrict__ W1F,
                     u16* __restrict__ W2F, u16* __restrict__ W3F,
                     float* __restrict__ fz, float* __restrict__ out2) {
  __shared__ float tile[64][65];
  const int bid = blockIdx.x, t = threadIdx.x;
  if (bid == 0 && t < 2) out2[t] = 0.f;
  if (bid < 512) {                                // ---- x: block = (b, ck) ----
    const int b = bid >> 3, ck = bid & 7;
    #pragma unroll
    for (int j = 0; j < 4; j++) {                 // coalesced fp32 tile (64c x 64p)
      int e4 = j * 1024 + t * 4;
      int c = e4 >> 6, p0 = e4 & 63;
      float4 v = *(const float4*)(x + ((size_t)b * 512 + ck * 64 + c) * 64 + p0);
      tile[c][p0] = v.x; tile[c][p0 + 1] = v.y; tile[c][p0 + 2] = v.z; tile[c][p0 + 3] = v.w;
    }
    __syncthreads();
    #pragma unroll
    for (int i = 0; i < 2; i++) {                 // 512 16B-slots
      int s = i * 256 + t;
      int ksl = s >> 7, ph = (s >> 6) & 1, lane = s & 63;
      int cb = ksl * 16 + (lane >> 5) * 8, pp = ph * 32 + (lane & 31);
      u16 o[8];
      #pragma unroll
      for (int jj = 0; jj < 8; jj++) o[jj] = f2bf(tile[cb + jj][pp]);
      *(uint4*)(xF + (((size_t)b * 64 + (ck * 4 + ksl) * 2 + ph) * 512) + lane * 8) = *(uint4*)o;
    }
  } else if (bid < 1312) {                        // ---- W1: 6400 frags ----
    int base = (bid - 512) * 512;
    #pragma unroll
    for (int i = 0; i < 2; i++) {
      int s = base + i * 256 + t;
      int frag = s >> 6, lane = s & 63;
      int k = frag >> 6, fr = frag & 63;
      int m = (fr & 1) * 32 + (lane & 31);
      int c0 = (fr >> 1) * 16 + (lane >> 5) * 8;
      const float* src = w1 + ((size_t)k * 64 + m) * 512 + c0;
      float4 a = *(const float4*)src, b4 = *(const float4*)(src + 4);
      u16 o[8] = { f2bf(a.x), f2bf(a.y), f2bf(a.z), f2bf(a.w),
                   f2bf(b4.x), f2bf(b4.y), f2bf(b4.z), f2bf(b4.w) };
      *(uint4*)(W1F + ((size_t)frag * 512) + lane * 8) = *(uint4*)o;
    }
  } else if (bid < 1512) {                        // ---- W2: 1600 frags ----
    int base = (bid - 1312) * 512;
    #pragma unroll
    for (int i = 0; i < 2; i++) {
      int s = base + i * 256 + t;
      int frag = s >> 6, lane = s & 63;
      int k = frag >> 4, fr = frag & 15;
      int m = (fr & 3) * 32 + (lane & 31);
      int c0 = (fr >> 2) * 16 + (lane >> 5) * 8;
      const float* src = w2 + ((size_t)k * 128 + m) * 64 + c0;
      float4 a = *(const float4*)src, b4 = *(const float4*)(src + 4);
      u16 o[8] = { f2bf(a.x), f2bf(a.y), f2bf(a.z), f2bf(a.w),
                   f2bf(b4.x), f2bf(b4.y), f2bf(b4.z), f2bf(b4.w) };
      *(uint4*)(W2F + ((size_t)frag * 512) + lane * 8) = *(uint4*)o;
    }
  } else if (bid < 1612) {                        // ---- W3: 800 frags ----
    int base = (bid - 1512) * 512;
    #pragma unroll
    for (int i = 0; i < 2; i++) {
      int s = base + i * 256 + t;
      int frag = s >> 6, lane = s & 63;
      int k = frag >> 3, kb = frag & 7;
      int m = lane & 31;
      int c0 = kb * 16 + (lane >> 5) * 8;
      const float* src = w3 + ((size_t)k * 32 + m) * 128 + c0;
      float4 a = *(const float4*)src, b4 = *(const float4*)(src + 4);
      u16 o[8] = { f2bf(a.x), f2bf(a.y), f2bf(a.z), f2bf(a.w),
                   f2bf(b4.x), f2bf(b4.y), f2bf(b4.z), f2bf(b4.w) };
      *(uint4*)(W3F + ((size_t)frag * 512) + lane * 8) = *(uint4*)o;
    }
  } else {                                        // ---- zero fw/f1w (12800 floats) ----
    int i4 = (bid - 1612) * 256 + t;
    if (i4 < 3200) {
      float4 z = {0.f, 0.f, 0.f, 0.f};
      *(float4*)(fz + (size_t)i4 * 4) = z;
    }
  }
}

// ============ in-register C/D -> B-fragment handoff (T12-style) ============
// acc reg g*4+q holds act-row r = q+8g+4h (h=lane>>5), col = lane&31.
// Output B-frag covers act-rows [GG*16, GG*16+16): elem (half h, col nn)[j] =
// bf16(tanh(act[GG*16 + h*8 + j][nn])). One permlane32_swap per packed pair.
template<int GG>
__device__ __forceinline__ s16x8 mk_bfrag(const f32x16 a) {
  u32 P0 = pk2bf(tanh_fast(a[8 * GG + 0]), tanh_fast(a[8 * GG + 1]));
  u32 P1 = pk2bf(tanh_fast(a[8 * GG + 2]), tanh_fast(a[8 * GG + 3]));
  u32 Q0 = pk2bf(tanh_fast(a[8 * GG + 4]), tanh_fast(a[8 * GG + 5]));
  u32 Q1 = pk2bf(tanh_fast(a[8 * GG + 6]), tanh_fast(a[8 * GG + 7]));
  asm("v_permlane32_swap_b32 %0, %1" : "+v"(P0), "+v"(Q0));
  asm("v_permlane32_swap_b32 %0, %1" : "+v"(P1), "+v"(Q1));
  int4 wv = { (int)P0, (int)P1, (int)Q0, (int)Q1 };   // (j0,j1)(j2,j3)(j4,j5)(j6,j7)
  return __builtin_bit_cast(s16x8, wv);
}

// ============ main: block = (k, b-pair); waves = (bq, ph) ============
// r3 structure: wave-PRIVATE x fragments load global->VGPR (Bn prefetch, no LDS
// round-trip -- they were 33% of stage-1 ds_reads + 60% of DMA with zero
// sharing); only SHARED W1/W2/W3 go through LDS via counted-vmcnt DMA dbuf.
// LDS 40 KB -> 4 blocks/CU; in-register T12 handoffs unchanged; barrier-free
// tail after W3 is resident.
__global__ __launch_bounds__(256, 4) void cssr_main(
    const u16* __restrict__ W1F, const u16* __restrict__ W2F, const u16* __restrict__ W3F,
    const u16* __restrict__ xF, const float* __restrict__ protos,
    const float* __restrict__ protos1, float* __restrict__ out,
    float* __restrict__ fw, float* __restrict__ f1w)
{
  // [0:4096) W1 buf0 | [4096:8192) W1 buf1 | [8192:16384) W2 | [16384:20480) W3
  __shared__ u16 pool[20480];          // 40 KB
  const int bid = blockIdx.x;
  const int k = bid >> 5, bpair = bid & 31;
  const int tid = threadIdx.x, w = tid >> 6, lane = tid & 63;
  const int bq = w >> 1, ph = w & 1;
  const int b = bpair * 2 + bq;
  const int h = lane >> 5, nn = lane & 31;

  const u16* xw  = xF  + ((size_t)b * 64) * 512 + lane * 8;   // + (gks*2+ph)*512
  const u16* w1w = W1F + ((size_t)k * 64) * 512 + lane * 8;   // + (gks*2+mt)*512

  // prologue: chunk 0 -- x B-frags to regs, W1 frags (wave w -> ksl=w) to LDS
  s16x8 Bc[4], Bn[4];
  #pragma unroll
  for (int ksl = 0; ksl < 4; ksl++)
    Bc[ksl] = *(const s16x8*)(xw + (ksl * 2 + ph) * 512);
  ld_lds16(w1w + (w * 2 + 0) * 512, &pool[(2 * w + 0) * 512]);
  ld_lds16(w1w + (w * 2 + 1) * 512, &pool[(2 * w + 1) * 512]);

  // ---------------- stage 1: h1 = tanh(W1[k] @ x[b])  per-wave M=64 N=32 K=512 ----
  f32x16 acc1[2] = {};
  #pragma unroll
  for (int ci = 0; ci < 8; ci++) {
    const int cb = ci & 1;
    if (ci < 7) {                      // prefetch chunk ci+1: 4 reg-loads + 2 DMA
      #pragma unroll
      for (int ksl = 0; ksl < 4; ksl++)
        Bn[ksl] = *(const s16x8*)(xw + (((ci + 1) * 4 + ksl) * 2 + ph) * 512);
      ld_lds16(w1w + (((ci + 1) * 4 + w) * 2 + 0) * 512, &pool[(cb ^ 1) * 4096 + (2 * w + 0) * 512]);
      ld_lds16(w1w + (((ci + 1) * 4 + w) * 2 + 1) * 512, &pool[(cb ^ 1) * 4096 + (2 * w + 1) * 512]);
    } else {                           // last chunk: stage W2 (4/wave) + W3 (2/wave)
      #pragma unroll
      for (int j = 0; j < 4; j++)
        ld_lds16(W2F + ((size_t)k * 16 + w * 4 + j) * 512 + lane * 8,
                 &pool[8192 + (w * 4 + j) * 512]);
      ld_lds16(W3F + ((size_t)k * 8 + w * 2 + 0) * 512 + lane * 8, &pool[16384 + (w * 2 + 0) * 512]);
      ld_lds16(W3F + ((size_t)k * 8 + w * 2 + 1) * 512 + lane * 8, &pool[16384 + (w * 2 + 1) * 512]);
    }
    VMCNT(6); BAR();                   // chunk ci resident; 6 newest stay in flight
    __builtin_amdgcn_s_setprio(1);
    #pragma unroll
    for (int ksl = 0; ksl < 4; ksl++) {
      s16x8 A0 = *(const s16x8*)&pool[cb * 4096 + (ksl * 2 + 0) * 512 + lane * 8];
      s16x8 A1 = *(const s16x8*)&pool[cb * 4096 + (ksl * 2 + 1) * 512 + lane * 8];
      acc1[0] = MFMA32(A0, Bc[ksl], acc1[0]);
      acc1[1] = MFMA32(A1, Bc[ksl], acc1[1]);
    }
    __builtin_amdgcn_s_setprio(0);
    if (ci < 7) {
      #pragma unroll
      for (int ksl = 0; ksl < 4; ksl++) Bc[ksl] = Bn[ksl];
      BAR();                           // reads of buf cb done -> reusable for DMA
    }
  }

  // handoff 1 (in-register, overlaps W2/W3 DMA): b1[kb] = h1 ch [kb*16,kb*16+16)
  s16x8 b1[4];
  b1[0] = mk_bfrag<0>(acc1[0]); b1[1] = mk_bfrag<1>(acc1[0]);
  b1[2] = mk_bfrag<0>(acc1[1]); b1[3] = mk_bfrag<1>(acc1[1]);

  VMCNT(2); BAR();                     // W2 resident (W3's 2 still in flight)

  // ---------------- stage 2: h2 = tanh(W2[k] @ h1)  per-wave M=128 N=32 K=64 ----
  f32x16 acc2[4] = {};
  __builtin_amdgcn_s_setprio(1);
  #pragma unroll
  for (int kb = 0; kb < 4; kb++) {
    #pragma unroll
    for (int m4 = 0; m4 < 4; m4++) {
      s16x8 A = *(const s16x8*)&pool[8192 + (kb * 4 + m4) * 512 + lane * 8];
      acc2[m4] = MFMA32(A, b1[kb], acc2[m4]);
    }
  }
  __builtin_amdgcn_s_setprio(0);

  VMCNT(0); BAR();                     // W3 resident; no barriers after this point

  // prefetch protos into regs (latency hides under handoff-2's 64 tanh)
  const int p = ph * 32 + nn;
  const float* pr  = protos  + (size_t)k * 2048 + p;
  const float* pr1 = protos1 + (size_t)k * 2048 + p;
  float prv[16], pr1v[16];
  #pragma unroll
  for (int g = 0; g < 4; g++) {
    #pragma unroll
    for (int q = 0; q < 4; q++) {
      int m = q + 8 * g + 4 * h;
      prv [g * 4 + q] = pr [m * 64];
      pr1v[g * 4 + q] = pr1[m * 64];
    }
  }

  // handoff 2
  s16x8 b2[8];
  b2[0] = mk_bfrag<0>(acc2[0]); b2[1] = mk_bfrag<1>(acc2[0]);
  b2[2] = mk_bfrag<0>(acc2[1]); b2[3] = mk_bfrag<1>(acc2[1]);
  b2[4] = mk_bfrag<0>(acc2[2]); b2[5] = mk_bfrag<1>(acc2[2]);
  b2[6] = mk_bfrag<0>(acc2[3]); b2[7] = mk_bfrag<1>(acc2[3]);

  // ---------------- stage 3: lt = tanh(W3[k] @ h2)  per-wave M=32 N=32 K=128 ----
  f32x16 acc3 = {};
  __builtin_amdgcn_s_setprio(1);
  #pragma unroll
  for (int kb = 0; kb < 8; kb++) {
    s16x8 A = *(const s16x8*)&pool[16384 + kb * 512 + lane * 8];
    acc3 = MFMA32(A, b2[kb], acc3);
  }
  __builtin_amdgcn_s_setprio(0);

  // ---------------- distances, clip, logits, f / f1 ----------------
  float d2 = 0.f, d21 = 0.f;
  #pragma unroll
  for (int g = 0; g < 4; g++) {
    #pragma unroll
    for (int q = 0; q < 4; q++) {
      float lt = tanh_fast(acc3[g * 4 + q]);
      float d = lt - prv [g * 4 + q];  d2  += d * d;
      float e = lt - pr1v[g * 4 + q];  d21 += e * e;
    }
  }
  d2 += __shfl_xor(d2, 32); d21 += __shfl_xor(d21, 32);
  float er  = fminf(fmaxf(d2  * -0.1f, -100.f), 100.f);
  float er1 = fminf(fmaxf(d21 * -0.1f, -100.f), 100.f);
  if (h == 0) {
    out[(size_t)b * 6400 + k * 64 + p]          = er;
    out[409600 + (size_t)b * 6400 + k * 64 + p] = er1;
  }
  float s = er, s1 = er1;
  s += __shfl_xor(s, 1);  s1 += __shfl_xor(s1, 1);
  s += __shfl_xor(s, 2);  s1 += __shfl_xor(s1, 2);
  s += __shfl_xor(s, 4);  s1 += __shfl_xor(s1, 4);
  s += __shfl_xor(s, 8);  s1 += __shfl_xor(s1, 8);
  s += __shfl_xor(s, 16); s1 += __shfl_xor(s1, 16);
  if (lane == 0) {
    atomicAdd(&fw [k * 64 + b], s);    // two waves (ph=0,1) contribute per (k,b)
    atomicAdd(&f1w[k * 64 + b], s1);
  }
}

// ============ finalize: per-k block, atomicAdd into out2 (zeroed in prep) ============
__global__ void finalize(const float* __restrict__ f, const float* __restrict__ f1,
                         const int* __restrict__ ycls, float* __restrict__ out2) {
  const int k = blockIdx.x, b = threadIdx.x;
  float fv = f[k * 64 + b], f1v = f1[k * 64 + b];
  bool eq = (ycls[b] == k);
  bool cb = (!eq) && (fv < 10000.f);
  float s1 = eq ? f1v : 0.f, ne = eq ? 1.f : 0.f;
  float s  = cb ? fv  : 0.f, nc = cb ? 1.f : 0.f;
  #pragma unroll
  for (int o = 1; o < 64; o <<= 1) {
    s1 += __shfl_xor(s1, o); ne += __shfl_xor(ne, o);
    s  += __shfl_xor(s,  o); nc += __shfl_xor(nc, o);
  }
  if (b == 0) {
    if (ne > 0.f) atomicAdd(&out2[0], s1 / ne);
    if (nc > 0.f) atomicAdd(&out2[1], s / nc);
  }
}

extern "C" void kernel_launch(void* const* d_in, const int* in_sizes, int n_in,
                              void* d_out, int out_size, void* d_ws, size_t ws_size,
                              hipStream_t stream) {
  const float* x     = (const float*)d_in[0];
  const int*   ycls  = (const int*)d_in[1];
  const float* W1    = (const float*)d_in[4];
  const float* W2    = (const float*)d_in[5];
  const float* W3    = (const float*)d_in[6];
  const float* prot  = (const float*)d_in[7];
  const float* prot1 = (const float*)d_in[8];
  float* out = (float*)d_out;

  char* ws = (char*)d_ws;
  u16*  xFb = (u16*)(ws);                        // 4,194,304 B
  u16*  W1F = (u16*)(ws + 4194304);              // 6,553,600 B
  u16*  W2F = (u16*)(ws + 10747904);             // 1,638,400 B
  u16*  W3F = (u16*)(ws + 12386304);             //   819,200 B
  float* fw  = (float*)(ws + 13205504);          // 25,600 B
  float* f1w = (float*)(ws + 13231104);          // 25,600 B (contiguous with fw)

  prep<<<1625, 256, 0, stream>>>(x, W1, W2, W3, xFb, W1F, W2F, W3F,
                                 fw, out + 819200);
  cssr_main<<<KCLS * 32, 256, 0, stream>>>(W1F, W2F, W3F, xFb, prot, prot1,
                                           out, fw, f1w);
  finalize<<<KCLS, 64, 0, stream>>>(fw, f1w, ycls, out + 819200);
}

// Round 4
// 141.166 us; speedup vs baseline: 1.0675x; 1.0056x over previous
//
#include <hip/hip_runtime.h>

typedef short  s16x8  __attribute__((ext_vector_type(8)));
typedef float  f32x16 __attribute__((ext_vector_type(16)));
typedef unsigned short u16;
typedef unsigned int   u32;
typedef unsigned long long u64b;

#define MFMA32(a,b,c) __builtin_amdgcn_mfma_f32_32x32x16_bf16((a),(b),(c),0,0,0)
#define KCLS 100
#define VMCNT(n) asm volatile("s_waitcnt vmcnt(" #n ")" ::: "memory")
#define BAR()    __builtin_amdgcn_s_barrier()

__device__ __forceinline__ u16 f2bf(float f) {
  return (u16)(__builtin_bit_cast(unsigned, f) >> 16);   // trunc; error budget huge
}

__device__ __forceinline__ u32 pk2bf(float lo, float hi) {   // trunc-pack 2 f32 -> 2 bf16
#if __has_builtin(__builtin_amdgcn_perm)
  // v_perm_b32: dst = {hi.b3, hi.b2, lo.b3, lo.b2}  (1 instr vs shr+and+or)
  return __builtin_amdgcn_perm(__builtin_bit_cast(u32, hi),
                               __builtin_bit_cast(u32, lo), 0x07060302u);
#else
  return (__builtin_bit_cast(u32, lo) >> 16) | (__builtin_bit_cast(u32, hi) & 0xffff0000u);
#endif
}

__device__ __forceinline__ float tanh_fast(float x) {
  float e = __builtin_amdgcn_exp2f(x * 2.8853900817779268f);
  return 1.0f - 2.0f * __builtin_amdgcn_rcpf(e + 1.0f);
}

__device__ __forceinline__ void ld_lds16(const void* g, void* l) {
  __builtin_amdgcn_global_load_lds(
      (const __attribute__((address_space(1))) unsigned char*)g,
      (__attribute__((address_space(3))) unsigned char*)l, 16, 0, 0);
}

// ============ prep: emit fragment-ordered bf16 tensors + zero accumulators ============
// Fragment = 1 KB: [lane64][8 bf16]; lane&31 = row/col-in-tile, lane>>5 = k-half.
// xF  [b][frag = gks*2+ph]   p = ph*32+(lane&31), c = gks*16+(lane>>5)*8+j
// W1F [k][frag = gks*2+mt]   m = mt*32+(lane&31), c as above
// W2F [k][frag = m4*4+kb]    m = m4*32+(lane&31), c = kb*16+(lane>>5)*8+j  (m4-MAJOR)
// W3F [k][frag = kb]         m = lane&31,         c = kb*16+(lane>>5)*8+j
__global__ void prep(const float* __restrict__ x, const float* __restrict__ w1,
                     const float* __restrict__ w2, const float* __restrict__ w3,
                     u16* __restrict__ xF, u16* __restrict__ W1F,
                     u16* __restrict__ W2F, u16* __restrict__ W3F,
                     float* __restrict__ fz, float* __restrict__ out2) {
  __shared__ float tile[64][65];
  const int bid = blockIdx.x, t = threadIdx.x;
  if (bid == 0 && t < 2) out2[t] = 0.f;
  if (bid < 512) {                                // ---- x: block = (b, ck) ----
    const int b = bid >> 3, ck = bid & 7;
    #pragma unroll
    for (int j = 0; j < 4; j++) {                 // coalesced fp32 tile (64c x 64p)
      int e4 = j * 1024 + t * 4;
      int c = e4 >> 6, p0 = e4 & 63;
      float4 v = *(const float4*)(x + ((size_t)b * 512 + ck * 64 + c) * 64 + p0);
      tile[c][p0] = v.x; tile[c][p0 + 1] = v.y; tile[c][p0 + 2] = v.z; tile[c][p0 + 3] = v.w;
    }
    __syncthreads();
    #pragma unroll
    for (int i = 0; i < 2; i++) {                 // 512 16B-slots
      int s = i * 256 + t;
      int ksl = s >> 7, ph = (s >> 6) & 1, lane = s & 63;
      int cb = ksl * 16 + (lane >> 5) * 8, pp = ph * 32 + (lane & 31);
      u16 o[8];
      #pragma unroll
      for (int jj = 0; jj < 8; jj++) o[jj] = f2bf(tile[cb + jj][pp]);
      *(uint4*)(xF + (((size_t)b * 64 + (ck * 4 + ksl) * 2 + ph) * 512) + lane * 8) = *(uint4*)o;
    }
  } else if (bid < 1312) {                        // ---- W1: 6400 frags ----
    int base = (bid - 512) * 512;
    #pragma unroll
    for (int i = 0; i < 2; i++) {
      int s = base + i * 256 + t;
      int frag = s >> 6, lane = s & 63;
      int k = frag >> 6, fr = frag & 63;
      int m = (fr & 1) * 32 + (lane & 31);
      int c0 = (fr >> 1) * 16 + (lane >> 5) * 8;
      const float* src = w1 + ((size_t)k * 64 + m) * 512 + c0;
      float4 a = *(const float4*)src, b4 = *(const float4*)(src + 4);
      u16 o[8] = { f2bf(a.x), f2bf(a.y), f2bf(a.z), f2bf(a.w),
                   f2bf(b4.x), f2bf(b4.y), f2bf(b4.z), f2bf(b4.w) };
      *(uint4*)(W1F + ((size_t)frag * 512) + lane * 8) = *(uint4*)o;
    }
  } else if (bid < 1512) {                        // ---- W2: 1600 frags (m4-major) ----
    int base = (bid - 1312) * 512;
    #pragma unroll
    for (int i = 0; i < 2; i++) {
      int s = base + i * 256 + t;
      int frag = s >> 6, lane = s & 63;
      int k = frag >> 4, fr = frag & 15;
      int m = (fr >> 2) * 32 + (lane & 31);       // fr = m4*4 + kb
      int c0 = (fr & 3) * 16 + (lane >> 5) * 8;
      const float* src = w2 + ((size_t)k * 128 + m) * 64 + c0;
      float4 a = *(const float4*)src, b4 = *(const float4*)(src + 4);
      u16 o[8] = { f2bf(a.x), f2bf(a.y), f2bf(a.z), f2bf(a.w),
                   f2bf(b4.x), f2bf(b4.y), f2bf(b4.z), f2bf(b4.w) };
      *(uint4*)(W2F + ((size_t)frag * 512) + lane * 8) = *(uint4*)o;
    }
  } else if (bid < 1612) {                        // ---- W3: 800 frags ----
    int base = (bid - 1512) * 512;
    #pragma unroll
    for (int i = 0; i < 2; i++) {
      int s = base + i * 256 + t;
      int frag = s >> 6, lane = s & 63;
      int k = frag >> 3, kb = frag & 7;
      int m = lane & 31;
      int c0 = kb * 16 + (lane >> 5) * 8;
      const float* src = w3 + ((size_t)k * 32 + m) * 128 + c0;
      float4 a = *(const float4*)src, b4 = *(const float4*)(src + 4);
      u16 o[8] = { f2bf(a.x), f2bf(a.y), f2bf(a.z), f2bf(a.w),
                   f2bf(b4.x), f2bf(b4.y), f2bf(b4.z), f2bf(b4.w) };
      *(uint4*)(W3F + ((size_t)frag * 512) + lane * 8) = *(uint4*)o;
    }
  } else {                                        // ---- zero fw/f1w (12800 floats) ----
    int i4 = (bid - 1612) * 256 + t;
    if (i4 < 3200) {
      float4 z = {0.f, 0.f, 0.f, 0.f};
      *(float4*)(fz + (size_t)i4 * 4) = z;
    }
  }
}

// ============ in-register C/D -> B-fragment handoff (T12-style) ============
// acc reg g*4+q holds act-row r = q+8g+4h (h=lane>>5), col = lane&31.
// Output B-frag covers act-rows [GG*16, GG*16+16): elem (half h, col nn)[j] =
// bf16(tanh(act[GG*16 + h*8 + j][nn])). One permlane32_swap per packed pair.
template<int GG>
__device__ __forceinline__ s16x8 mk_bfrag(const f32x16 a) {
  u32 P0 = pk2bf(tanh_fast(a[8 * GG + 0]), tanh_fast(a[8 * GG + 1]));
  u32 P1 = pk2bf(tanh_fast(a[8 * GG + 2]), tanh_fast(a[8 * GG + 3]));
  u32 Q0 = pk2bf(tanh_fast(a[8 * GG + 4]), tanh_fast(a[8 * GG + 5]));
  u32 Q1 = pk2bf(tanh_fast(a[8 * GG + 6]), tanh_fast(a[8 * GG + 7]));
  asm("v_permlane32_swap_b32 %0, %1" : "+v"(P0), "+v"(Q0));
  asm("v_permlane32_swap_b32 %0, %1" : "+v"(P1), "+v"(Q1));
  int4 wv = { (int)P0, (int)P1, (int)Q0, (int)Q1 };   // (j0,j1)(j2,j3)(j4,j5)(j6,j7)
  return __builtin_bit_cast(s16x8, wv);
}

// ============ main: block = (k, b-pair); waves = (bq, ph) ============
// r4 structure: ONE 11-chunk DMA stream (8 W1 + 2 W2[m4-major] + 1 W3) through
// FOUR rotating 8 KB LDS buffers -> 2-deep prefetch, ONE barrier per chunk
// (4-buf rotation makes DMA(ci+2) target chunk ci-2's buffer, whose reads
// finished before BAR(ci-1)). vmcnt counted per the issue queue, never drained
// mid-stream. Stage 2 is m4-sequential: acc2t (16 regs) completes and converts
// to its 2 b2 frags immediately -- peak combined regs ~111 (4 waves/SIMD).
__global__ __launch_bounds__(256, 4) void cssr_main(
    const u16* __restrict__ W1F, const u16* __restrict__ W2F, const u16* __restrict__ W3F,
    const u16* __restrict__ xF, const float* __restrict__ protos,
    const float* __restrict__ protos1, float* __restrict__ out,
    float* __restrict__ fw, float* __restrict__ f1w)
{
  __shared__ u16 pool[4][4096];        // 4 x 8 KB rotating chunk buffers
  const int bid = blockIdx.x;
  const int k = bid >> 5, bpair = bid & 31;
  const int tid = threadIdx.x, w = tid >> 6, lane = tid & 63;
  const int bq = w >> 1, ph = w & 1;
  const int b = bpair * 2 + bq;
  const int h = lane >> 5, nn = lane & 31;

  const u16* xw  = xF  + ((size_t)b * 64) * 512 + lane * 8;   // + (gks*2+ph)*512
  const u16* w1w = W1F + ((size_t)k * 64) * 512 + lane * 8;   // + (ci*8 + 2w+j)*512
  const u16* w2w = W2F + ((size_t)k * 16) * 512 + lane * 8;
  const u16* w3w = W3F + ((size_t)k * 8)  * 512 + lane * 8;

  // per-chunk DMA: wave w stages local frags 2w, 2w+1 (2 x 1 KB)
  #define DMA_W1(c) { ld_lds16(w1w + ((c) * 8 + 2 * w + 0) * 512, &pool[(c) & 3][(2 * w + 0) * 512]); \
                      ld_lds16(w1w + ((c) * 8 + 2 * w + 1) * 512, &pool[(c) & 3][(2 * w + 1) * 512]); }

  // prologue: B(0) regs, then DMA chunks 0,1   (queue: B0,D0,D1)
  s16x8 Bst[2][4];
  #pragma unroll
  for (int ksl = 0; ksl < 4; ksl++)
    Bst[0][ksl] = *(const s16x8*)(xw + (ksl * 2 + ph) * 512);
  DMA_W1(0); DMA_W1(1);

  // ---------------- stage 1: h1 = tanh(W1[k] @ x[b])  per-wave M=64 N=32 K=512 ----
  f32x16 acc1[2] = {};
  #pragma unroll
  for (int ci = 0; ci < 7; ci++) {     // its 0..6: issue B(ci+1) + DMA(ci+2)
    #pragma unroll
    for (int ksl = 0; ksl < 4; ksl++)
      Bst[(ci + 1) & 1][ksl] = *(const s16x8*)(xw + (((ci + 1) * 4 + ksl) * 2 + ph) * 512);
    if (ci < 6) {
      DMA_W1(ci + 2);
    } else {                           // chunk 8 = W2 frags 0..7 (m4 = 0,1) -> buf0
      ld_lds16(w2w + (2 * w + 0) * 512, &pool[0][(2 * w + 0) * 512]);
      ld_lds16(w2w + (2 * w + 1) * 512, &pool[0][(2 * w + 1) * 512]);
    }
    VMCNT(8); BAR();                   // chunk ci + B(ci) resident; 8 newest in flight
    __builtin_amdgcn_s_setprio(1);
    #pragma unroll
    for (int ksl = 0; ksl < 4; ksl++) {
      s16x8 A0 = *(const s16x8*)&pool[ci & 3][(ksl * 2 + 0) * 512 + lane * 8];
      s16x8 A1 = *(const s16x8*)&pool[ci & 3][(ksl * 2 + 1) * 512 + lane * 8];
      acc1[0] = MFMA32(A0, Bst[ci & 1][ksl], acc1[0]);
      acc1[1] = MFMA32(A1, Bst[ci & 1][ksl], acc1[1]);
    }
    __builtin_amdgcn_s_setprio(0);
  }
  // it7: issue chunk 9 = W2 frags 8..15 (m4 = 2,3) -> buf1
  ld_lds16(w2w + (8 + 2 * w + 0) * 512, &pool[1][(2 * w + 0) * 512]);
  ld_lds16(w2w + (8 + 2 * w + 1) * 512, &pool[1][(2 * w + 1) * 512]);
  VMCNT(4); BAR();                     // chunk7 + B(7) resident (D8,D9 in flight)
  __builtin_amdgcn_s_setprio(1);
  #pragma unroll
  for (int ksl = 0; ksl < 4; ksl++) {
    s16x8 A0 = *(const s16x8*)&pool[3][(ksl * 2 + 0) * 512 + lane * 8];
    s16x8 A1 = *(const s16x8*)&pool[3][(ksl * 2 + 1) * 512 + lane * 8];
    acc1[0] = MFMA32(A0, Bst[1][ksl], acc1[0]);
    acc1[1] = MFMA32(A1, Bst[1][ksl], acc1[1]);
  }
  __builtin_amdgcn_s_setprio(0);

  // it8: issue chunk 10 = W3 frags 0..7 -> buf2; handoff-1 VALU overlaps DMA
  ld_lds16(w3w + (2 * w + 0) * 512, &pool[2][(2 * w + 0) * 512]);
  ld_lds16(w3w + (2 * w + 1) * 512, &pool[2][(2 * w + 1) * 512]);

  s16x8 b1[4];                         // b1[kb] = h1 channels [kb*16, kb*16+16)
  b1[0] = mk_bfrag<0>(acc1[0]); b1[1] = mk_bfrag<1>(acc1[0]);
  b1[2] = mk_bfrag<0>(acc1[1]); b1[3] = mk_bfrag<1>(acc1[1]);

  VMCNT(4); BAR();                     // chunk8 (W2 lo) resident; D9,D10 in flight

  // ---------------- stage 2a: h2[m4=0,1], m4-sequential, b2 built in place ----
  s16x8 b2[8];
  #pragma unroll
  for (int m4l = 0; m4l < 2; m4l++) {
    f32x16 a2 = {};
    __builtin_amdgcn_s_setprio(1);
    #pragma unroll
    for (int kb = 0; kb < 4; kb++) {   // A frag local = m4l*4+kb (m4-major layout)
      s16x8 A = *(const s16x8*)&pool[0][(m4l * 4 + kb) * 512 + lane * 8];
      a2 = MFMA32(A, b1[kb], a2);
    }
    __builtin_amdgcn_s_setprio(0);
    b2[m4l * 2 + 0] = mk_bfrag<0>(a2);
    b2[m4l * 2 + 1] = mk_bfrag<1>(a2);
  }

  // it9: issue proto loads (32, stay in flight past the vmcnt)
  const int p = ph * 32 + nn;
  const float* pr  = protos  + (size_t)k * 2048 + p;
  const float* pr1 = protos1 + (size_t)k * 2048 + p;
  float prv[16], pr1v[16];
  #pragma unroll
  for (int g = 0; g < 4; g++) {
    #pragma unroll
    for (int q = 0; q < 4; q++) {
      int m = q + 8 * g + 4 * h;
      prv [g * 4 + q] = pr [m * 64];
      pr1v[g * 4 + q] = pr1[m * 64];
    }
  }
  VMCNT(34); BAR();                    // chunk9 (W2 hi) resident; D10 + protos fly

  // ---------------- stage 2b: h2[m4=2,3] ----
  #pragma unroll
  for (int m4l = 0; m4l < 2; m4l++) {
    f32x16 a2 = {};
    __builtin_amdgcn_s_setprio(1);
    #pragma unroll
    for (int kb = 0; kb < 4; kb++) {
      s16x8 A = *(const s16x8*)&pool[1][(m4l * 4 + kb) * 512 + lane * 8];
      a2 = MFMA32(A, b1[kb], a2);
    }
    __builtin_amdgcn_s_setprio(0);
    b2[4 + m4l * 2 + 0] = mk_bfrag<0>(a2);
    b2[4 + m4l * 2 + 1] = mk_bfrag<1>(a2);
  }

  VMCNT(32); BAR();                    // chunk10 (W3) resident; protos still fly

  // ---------------- stage 3: lt = tanh(W3[k] @ h2)  per-wave M=32 N=32 K=128 ----
  f32x16 acc3 = {};
  __builtin_amdgcn_s_setprio(1);
  #pragma unroll
  for (int kb = 0; kb < 8; kb++) {
    s16x8 A = *(const s16x8*)&pool[2][kb * 512 + lane * 8];
    acc3 = MFMA32(A, b2[kb], acc3);
  }
  __builtin_amdgcn_s_setprio(0);

  // ---------------- distances, clip, logits, f / f1 ----------------
  float d2 = 0.f, d21 = 0.f;
  #pragma unroll
  for (int g = 0; g < 4; g++) {
    #pragma unroll
    for (int q = 0; q < 4; q++) {
      float lt = tanh_fast(acc3[g * 4 + q]);
      float d = lt - prv [g * 4 + q];  d2  += d * d;
      float e = lt - pr1v[g * 4 + q];  d21 += e * e;
    }
  }
  d2 += __shfl_xor(d2, 32); d21 += __shfl_xor(d21, 32);
  float er  = fminf(fmaxf(d2  * -0.1f, -100.f), 100.f);
  float er1 = fminf(fmaxf(d21 * -0.1f, -100.f), 100.f);
  if (h == 0) {
    out[(size_t)b * 6400 + k * 64 + p]          = er;
    out[409600 + (size_t)b * 6400 + k * 64 + p] = er1;
  }
  float s = er, s1 = er1;
  s += __shfl_xor(s, 1);  s1 += __shfl_xor(s1, 1);
  s += __shfl_xor(s, 2);  s1 += __shfl_xor(s1, 2);
  s += __shfl_xor(s, 4);  s1 += __shfl_xor(s1, 4);
  s += __shfl_xor(s, 8);  s1 += __shfl_xor(s1, 8);
  s += __shfl_xor(s, 16); s1 += __shfl_xor(s1, 16);
  if (lane == 0) {
    atomicAdd(&fw [k * 64 + b], s);    // two waves (ph=0,1) contribute per (k,b)
    atomicAdd(&f1w[k * 64 + b], s1);
  }
  #undef DMA_W1
}

// ============ finalize: per-k block, atomicAdd into out2 (zeroed in prep) ============
__global__ void finalize(const float* __restrict__ f, const float* __restrict__ f1,
                         const int* __restrict__ ycls, float* __restrict__ out2) {
  const int k = blockIdx.x, b = threadIdx.x;
  float fv = f[k * 64 + b], f1v = f1[k * 64 + b];
  bool eq = (ycls[b] == k);
  bool cb = (!eq) && (fv < 10000.f);
  float s1 = eq ? f1v : 0.f, ne = eq ? 1.f : 0.f;
  float s  = cb ? fv  : 0.f, nc = cb ? 1.f : 0.f;
  #pragma unroll
  for (int o = 1; o < 64; o <<= 1) {
    s1 += __shfl_xor(s1, o); ne += __shfl_xor(ne, o);
    s  += __shfl_xor(s,  o); nc += __shfl_xor(nc, o);
  }
  if (b == 0) {
    if (ne > 0.f) atomicAdd(&out2[0], s1 / ne);
    if (nc > 0.f) atomicAdd(&out2[1], s / nc);
  }
}

extern "C" void kernel_launch(void* const* d_in, const int* in_sizes, int n_in,
                              void* d_out, int out_size, void* d_ws, size_t ws_size,
                              hipStream_t stream) {
  const float* x     = (const float*)d_in[0];
  const int*   ycls  = (const int*)d_in[1];
  const float* W1    = (const float*)d_in[4];
  const float* W2    = (const float*)d_in[5];
  const float* W3    = (const float*)d_in[6];
  const float* prot  = (const float*)d_in[7];
  const float* prot1 = (const float*)d_in[8];
  float* out = (float*)d_out;

  char* ws = (char*)d_ws;
  u16*  xFb = (u16*)(ws);                        // 4,194,304 B
  u16*  W1F = (u16*)(ws + 4194304);              // 6,553,600 B
  u16*  W2F = (u16*)(ws + 10747904);             // 1,638,400 B
  u16*  W3F = (u16*)(ws + 12386304);             //   819,200 B
  float* fw  = (float*)(ws + 13205504);          // 25,600 B
  float* f1w = (float*)(ws + 13231104);          // 25,600 B (contiguous with fw)

  prep<<<1625, 256, 0, stream>>>(x, W1, W2, W3, xFb, W1F, W2F, W3F,
                                 fw, out + 819200);
  cssr_main<<<KCLS * 32, 256, 0, stream>>>(W1F, W2F, W3F, xFb, prot, prot1,
                                           out, fw, f1w);
  finalize<<<KCLS, 64, 0, stream>>>(fw, f1w, ycls, out + 819200);
}